// Round 4
// baseline (256.646 us; speedup 1.0000x reference)
//
#include <hip/hip_runtime.h>

#define LOG2E 1.4426950408889634f

typedef __attribute__((ext_vector_type(8))) short short8;
typedef __attribute__((ext_vector_type(4))) float f32x4;
using u32 = unsigned int;
using u16 = unsigned short;
using u64 = unsigned long long;

// ---------------------------------------------------------------------------
// Kernel P: pack adj (4096x4096 int32 0/1) into transposed bitmask.
// 4 independent nt-loads per iter (ILP=4, ~128 loads in flight per CU) so the
// 64 MB read runs at HBM BW instead of 1-outstanding latency (~2.8 TB/s cap).
// ---------------------------------------------------------------------------
__global__ __launch_bounds__(256) void pack_mask_kernel(const int* __restrict__ adj,
                                                        u32* __restrict__ mask_t) {
    const int wid = (blockIdx.x * 256 + threadIdx.x) >> 6;
    const int lane = threadIdx.x & 63;
    for (int t = wid; t < 65536; t += 8192) {          // task = (row, 4-chunk group)
        const int r = t >> 4, c4 = t & 15;
        const int* base = adj + (size_t)r * 4096 + c4 * 256 + lane;
        int v0 = __builtin_nontemporal_load(base);
        int v1 = __builtin_nontemporal_load(base + 64);
        int v2 = __builtin_nontemporal_load(base + 128);
        int v3 = __builtin_nontemporal_load(base + 192);
        u64 b0 = __ballot(v0 > 0);
        u64 b1 = __ballot(v1 > 0);
        u64 b2 = __ballot(v2 > 0);
        u64 b3 = __ballot(v3 > 0);
        if (lane < 8) {                                 // lane k stores word-col c4*8+k
            u64 bv = (lane & 4) ? ((lane & 2) ? b3 : b2) : ((lane & 2) ? b1 : b0);
            u32 w = (u32)(bv >> ((lane & 1) << 5));
            mask_t[(size_t)(c4 * 8 + lane) * 4096 + r] = w;
        }
    }
}

// ---------------------------------------------------------------------------
// Kernel 1: h-partial = x @ W over one K-segment (unchanged this round).
// ---------------------------------------------------------------------------
__global__ __launch_bounds__(256) void k1_xw(const float* __restrict__ x,
                                             const float* __restrict__ W,
                                             float* __restrict__ ph,
                                             int TILES) {
    __shared__ float xs[64][36];
    __shared__ float ws[32][64];
    const int b = blockIdx.y, rt = blockIdx.x, ks = blockIdx.z;
    const int tid = threadIdx.x;
    const int rg = tid >> 4, cg = tid & 15;
    const int r0 = rg * 4, c0 = cg * 4;
    const int kt0 = ks * TILES;
    const float* xb = x + ((size_t)b * 4096 + (size_t)rt * 64) * 512;

    float acc[4][4];
#pragma unroll
    for (int i = 0; i < 4; i++)
#pragma unroll
        for (int j = 0; j < 4; j++) acc[i][j] = 0.f;

    float4 px[2], pw[2];
#pragma unroll
    for (int it = 0; it < 2; it++) {
        int c = tid + it * 256;
        px[it] = *(const float4*)(xb + (size_t)(c >> 3) * 512 + kt0 * 32 + ((c & 7) << 2));
        pw[it] = *(const float4*)(W + (size_t)(kt0 * 32 + (c >> 4)) * 64 + ((c & 15) << 2));
    }
    for (int kt = kt0; kt < kt0 + TILES; kt++) {
        __syncthreads();
#pragma unroll
        for (int it = 0; it < 2; it++) {
            int c = tid + it * 256;
            *(float4*)&xs[c >> 3][(c & 7) << 2] = px[it];
            *(float4*)&ws[c >> 4][(c & 15) << 2] = pw[it];
        }
        __syncthreads();
        if (kt < kt0 + TILES - 1) {
            int k0 = (kt + 1) * 32;
#pragma unroll
            for (int it = 0; it < 2; it++) {
                int c = tid + it * 256;
                px[it] = *(const float4*)(xb + (size_t)(c >> 3) * 512 + k0 + ((c & 7) << 2));
                pw[it] = *(const float4*)(W + (size_t)(k0 + (c >> 4)) * 64 + ((c & 15) << 2));
            }
        }
#pragma unroll
        for (int k4 = 0; k4 < 32; k4 += 4) {
            float4 xv[4], wv[4];
#pragma unroll
            for (int rr = 0; rr < 4; rr++) xv[rr] = *(const float4*)&xs[r0 + rr][k4];
#pragma unroll
            for (int kk = 0; kk < 4; kk++) wv[kk] = *(const float4*)&ws[k4 + kk][c0];
#pragma unroll
            for (int rr = 0; rr < 4; rr++)
#pragma unroll
                for (int kk = 0; kk < 4; kk++) {
                    const float xvv = ((const float*)&xv[rr])[kk];
#pragma unroll
                    for (int cc = 0; cc < 4; cc++)
                        acc[rr][cc] = fmaf(xvv, ((const float*)&wv[kk])[cc], acc[rr][cc]);
                }
        }
    }
    float* pb = ph + (((size_t)(ks * 4 + b) * 4096) + rt * 64) * 64;
#pragma unroll
    for (int rr = 0; rr < 4; rr++)
        *(float4*)&pb[(size_t)(r0 + rr) * 64 + c0] = *(float4*)&acc[rr][0];
}

// ---------------------------------------------------------------------------
// Kernel 1c: sum K-split partials (templated, all loads unrolled for ILP at
// the 1-WG/CU occupancy); epilogue: s1/s2 (pre-scaled), h^T bf16.
// ---------------------------------------------------------------------------
template <int KS>
__global__ __launch_bounds__(256) void k1c_fin(const float* __restrict__ ph,
                                               const float* __restrict__ a,
                                               u16* __restrict__ h_t,
                                               float* __restrict__ s1p,
                                               float* __restrict__ s2p) {
    const int b = blockIdx.y, rt = blockIdx.x;
    const int tid = threadIdx.x;
    const int rg = tid >> 4, cg = tid & 15;
    const int r0 = rg * 4, c0 = cg * 4;

    float4 v[KS][4];
#pragma unroll
    for (int s = 0; s < KS; s++) {
        const float* pb = ph + (((size_t)(s * 4 + b) * 4096) + rt * 64) * 64;
#pragma unroll
        for (int rr = 0; rr < 4; rr++)
            v[s][rr] = *(const float4*)&pb[(size_t)(r0 + rr) * 64 + c0];
    }
    float acc[4][4];
#pragma unroll
    for (int rr = 0; rr < 4; rr++) {
        acc[rr][0] = acc[rr][1] = acc[rr][2] = acc[rr][3] = 0.f;
#pragma unroll
        for (int s = 0; s < KS; s++) {
            acc[rr][0] += v[s][rr].x; acc[rr][1] += v[s][rr].y;
            acc[rr][2] += v[s][rr].z; acc[rr][3] += v[s][rr].w;
        }
    }
    float s1v[4], s2v[4];
#pragma unroll
    for (int rr = 0; rr < 4; rr++) { s1v[rr] = 0.f; s2v[rr] = 0.f; }
#pragma unroll
    for (int cc = 0; cc < 4; cc++) {
        float a1 = a[c0 + cc], a2 = a[64 + c0 + cc];
#pragma unroll
        for (int rr = 0; rr < 4; rr++) {
            s1v[rr] = fmaf(acc[rr][cc], a1, s1v[rr]);
            s2v[rr] = fmaf(acc[rr][cc], a2, s2v[rr]);
        }
    }
#pragma unroll
    for (int d = 1; d < 16; d <<= 1) {
#pragma unroll
        for (int rr = 0; rr < 4; rr++) {
            s1v[rr] += __shfl_xor(s1v[rr], d);
            s2v[rr] += __shfl_xor(s2v[rr], d);
        }
    }
    if (cg == 0) {
#pragma unroll
        for (int rr = 0; rr < 4; rr++) {
            int row = rt * 64 + r0 + rr;
            s1p[b * 4096 + row] = s1v[rr] * LOG2E;
            s2p[b * 4096 + row] = s2v[rr] * LOG2E;
        }
    }
#pragma unroll
    for (int cc = 0; cc < 4; cc++) {
        u32 b0 = __float_as_uint(acc[0][cc]) + 0x8000u;
        u32 b1 = __float_as_uint(acc[1][cc]) + 0x8000u;
        u32 b2 = __float_as_uint(acc[2][cc]) + 0x8000u;
        u32 b3 = __float_as_uint(acc[3][cc]) + 0x8000u;
        uint2 u;
        u.x = (b0 >> 16) | (b1 & 0xffff0000u);
        u.y = (b2 >> 16) | (b3 & 0xffff0000u);
        *(uint2*)(h_t + ((size_t)(b * 64 + c0 + cc)) * 4096 + rt * 64 + r0) = u;
    }
}

// ---------------------------------------------------------------------------
// Kernel 2: fused masked-softmax-numerator GEMM, barrier-free, no LDS.
// Mask words for a 16-step block preloaded into registers BEFORE the K-loop
// (the round-3 regression: mask loaded newest each iter forced a full drain
// before the weight build). B-frags direct from L2-resident h_t, ping-pong
// issued at iteration top, consumed at iteration end (~350 cyc window).
// s2 read directly (L1-resident stream) - no LDS, no __syncthreads at all.
// ---------------------------------------------------------------------------
template <int NSTEP>
__global__ __launch_bounds__(256, 4) void k2_attn(const u16* __restrict__ h_t,
                                                  const u32* __restrict__ mask_t,
                                                  const float* __restrict__ s1p,
                                                  const float* __restrict__ s2p,
                                                  float* __restrict__ part,
                                                  float* __restrict__ lp) {
    constexpr int JSEG = NSTEP * 32;
    const int b = blockIdx.y, seg = blockIdx.z, rb = blockIdx.x;
    const int tid = threadIdx.x, wave = tid >> 6, lane = tid & 63;
    const int m = lane & 15, quad = lane >> 4;
    const int row = rb * 64 + wave * 16 + m;
    const int jstart = seg * JSEG;
    const float t1 = s1p[b * 4096 + row];
    const u16* hb0 = h_t + ((size_t)b * 64 + m) * 4096 + jstart + quad * 8;
    const u32* mrow = mask_t + (size_t)(jstart >> 5) * 4096 + row;
    const float* s2b = s2p + (size_t)b * 4096 + jstart + quad * 8;

    f32x4 acc[4];
#pragma unroll
    for (int ot = 0; ot < 4; ot++) acc[ot] = (f32x4){0.f, 0.f, 0.f, 0.f};
    float lsA = 0.f, lsB = 0.f;

    union BU { uint4 q; short8 v; };
    BU bf[2][4];
    float4 s2r[2][2];
#pragma unroll
    for (int ot = 0; ot < 4; ot++)
        bf[0][ot].q = *(const uint4*)(hb0 + (size_t)ot * 16 * 4096);
    s2r[0][0] = *(const float4*)(s2b);
    s2r[0][1] = *(const float4*)(s2b + 4);

    for (int blk = 0; blk < NSTEP / 16; ++blk) {
        u32 mw[16];
#pragma unroll
        for (int s = 0; s < 16; s++) mw[s] = mrow[(size_t)(blk * 16 + s) * 4096];
#pragma unroll
        for (int s = 0; s < 16; s++) {
            const int js = blk * 16 + s;
            const int cur = js & 1, nxt = cur ^ 1;
            if (js + 1 < NSTEP) {      // prefetch next 32-j step (B-frags + s2)
#pragma unroll
                for (int ot = 0; ot < 4; ot++)
                    bf[nxt][ot].q = *(const uint4*)(hb0 + (js + 1) * 32 + (size_t)ot * 16 * 4096);
                s2r[nxt][0] = *(const float4*)(s2b + (js + 1) * 32);
                s2r[nxt][1] = *(const float4*)(s2b + (js + 1) * 32 + 4);
            }
            const u32 mws = mw[s] >> (quad * 8);
            const float sv[8] = {s2r[cur][0].x, s2r[cur][0].y, s2r[cur][0].z, s2r[cur][0].w,
                                 s2r[cur][1].x, s2r[cur][1].y, s2r[cur][1].z, s2r[cur][1].w};
            union { u32 u[4]; short8 v; } af;
#pragma unroll
            for (int p = 0; p < 4; p++) {
                float t0 = t1 + sv[2 * p];
                float u0 = fmaxf(t0, 0.2f * t0);                  // leaky-relu (log2 domain)
                float w0 = __builtin_amdgcn_exp2f(u0);
                u32 m0 = (u32)(((int)(mws << (31 - 2 * p))) >> 31);  // bit -> all-ones/0
                u32 w0u = __float_as_uint(w0) & m0;               // masked -> +0.0
                float t2 = t1 + sv[2 * p + 1];
                float u2 = fmaxf(t2, 0.2f * t2);
                float w1 = __builtin_amdgcn_exp2f(u2);
                u32 m1 = (u32)(((int)(mws << (30 - 2 * p))) >> 31);
                u32 w1u = __float_as_uint(w1) & m1;
                lsA += __uint_as_float(w0u);                      // denom (pre-round)
                lsB += __uint_as_float(w1u);
                // round-to-nearest bf16 pack: hi16 of (w+0x8000)
                af.u[p] = __builtin_amdgcn_perm(w1u + 0x8000u, w0u + 0x8000u, 0x07060302u);
            }
#pragma unroll
            for (int ot = 0; ot < 4; ot++)
                acc[ot] = __builtin_amdgcn_mfma_f32_16x16x32_bf16(af.v, bf[cur][ot].v,
                                                                  acc[ot], 0, 0, 0);
        }
    }
    // C/D layout: col=lane&15 (=o sub-index), row=quad*4+reg (=attention row)
    float* pb = part + (((size_t)(seg * 4 + b) * 4096) + rb * 64 + wave * 16) * 64;
#pragma unroll
    for (int ot = 0; ot < 4; ot++)
#pragma unroll
        for (int r = 0; r < 4; r++)
            pb[(quad * 4 + r) * 64 + ot * 16 + m] = acc[ot][r];
    lp[((size_t)(seg * 4 + b) * 4096 + row) * 4 + quad] = lsA + lsB;
}

// ---------------------------------------------------------------------------
// Kernel 3: combine j-split partials, normalize, elu. Templated S, loads
// unrolled upfront (16 independent 16B loads in flight).
// ---------------------------------------------------------------------------
template <int S>
__global__ __launch_bounds__(256) void k3_fin(const float* __restrict__ part,
                                              const float* __restrict__ lp,
                                              float* __restrict__ out) {
    int idx = blockIdx.x * 256 + threadIdx.x;    // 262144 = 4*4096*16
    int o4 = (idx & 15) << 2;
    int bi = idx >> 4;
    float4 pv[S], lv[S];
#pragma unroll
    for (int s = 0; s < S; s++) {
        pv[s] = *(const float4*)&part[((size_t)s * 16384 + bi) * 64 + o4];
        lv[s] = *(const float4*)&lp[((size_t)s * 16384 + bi) * 4];
    }
    float p0 = 0.f, p1 = 0.f, p2 = 0.f, p3 = 0.f, l = 0.f;
#pragma unroll
    for (int s = 0; s < S; s++) {
        p0 += pv[s].x; p1 += pv[s].y; p2 += pv[s].z; p3 += pv[s].w;
        l += (lv[s].x + lv[s].y) + (lv[s].z + lv[s].w);
    }
    float rl = 1.f / l;
    p0 *= rl; p1 *= rl; p2 *= rl; p3 *= rl;
    float4 o;
    o.x = p0 > 0.f ? p0 : __builtin_amdgcn_exp2f(p0 * LOG2E) - 1.f;
    o.y = p1 > 0.f ? p1 : __builtin_amdgcn_exp2f(p1 * LOG2E) - 1.f;
    o.z = p2 > 0.f ? p2 : __builtin_amdgcn_exp2f(p2 * LOG2E) - 1.f;
    o.w = p3 > 0.f ? p3 : __builtin_amdgcn_exp2f(p3 * LOG2E) - 1.f;
    *(float4*)&out[(size_t)bi * 64 + o4] = o;
}

// ---------------------------------------------------------------------------
extern "C" void kernel_launch(void* const* d_in, const int* in_sizes, int n_in,
                              void* d_out, int out_size, void* d_ws, size_t ws_size,
                              hipStream_t stream) {
    const float* x  = (const float*)d_in[0];
    const int* adj  = (const int*)d_in[1];
    const float* W  = (const float*)d_in[2];
    const float* a  = (const float*)d_in[3];
    float* out = (float*)d_out;
    char* ws = (char*)d_ws;

    // workspace layout
    u16* h_t   = (u16*)ws;                         // 2 MB
    u32* maskt = (u32*)(ws + (2 << 20));           // 2 MB
    float* s1p = (float*)(ws + (4 << 20));         // 64 KB
    float* s2p = s1p + 16384;                      // 64 KB
    float* lp  = s2p + 16384;                      // S*256 KB
    size_t base = (4u << 20) + 2 * 65536;
    int S = 8;                                     // k2 j-split
    while (S > 1 && base + (size_t)S * (262144 + 4194304) > ws_size) S >>= 1;
    float* part = (float*)(ws + base + (size_t)S * 262144);   // S*4 MB
    // k1 K-split partials alias the part buffer (free until k2 writes it)
    int KS = 4;
    while (KS > 1 && base + (size_t)S * 262144 + (size_t)KS * 4194304 > ws_size) KS >>= 1;

    pack_mask_kernel<<<2048, 256, 0, stream>>>(adj, maskt);
    k1_xw<<<dim3(64, 4, KS), 256, 0, stream>>>(x, W, part, 16 / KS);
    if (KS == 4)      k1c_fin<4><<<dim3(64, 4), 256, 0, stream>>>(part, a, h_t, s1p, s2p);
    else if (KS == 2) k1c_fin<2><<<dim3(64, 4), 256, 0, stream>>>(part, a, h_t, s1p, s2p);
    else              k1c_fin<1><<<dim3(64, 4), 256, 0, stream>>>(part, a, h_t, s1p, s2p);
    if (S == 8)      k2_attn<16><<<dim3(64, 4, 8), 256, 0, stream>>>(h_t, maskt, s1p, s2p, part, lp);
    else if (S == 4) k2_attn<32><<<dim3(64, 4, 4), 256, 0, stream>>>(h_t, maskt, s1p, s2p, part, lp);
    else if (S == 2) k2_attn<64><<<dim3(64, 4, 2), 256, 0, stream>>>(h_t, maskt, s1p, s2p, part, lp);
    else             k2_attn<128><<<dim3(64, 4, 1), 256, 0, stream>>>(h_t, maskt, s1p, s2p, part, lp);
    if (S == 8)      k3_fin<8><<<1024, 256, 0, stream>>>(part, lp, out);
    else if (S == 4) k3_fin<4><<<1024, 256, 0, stream>>>(part, lp, out);
    else if (S == 2) k3_fin<2><<<1024, 256, 0, stream>>>(part, lp, out);
    else             k3_fin<1><<<1024, 256, 0, stream>>>(part, lp, out);
}

// Round 6
// 224.924 us; speedup vs baseline: 1.1410x; 1.1410x over previous
//
#include <hip/hip_runtime.h>

#define LOG2E 1.4426950408889634f

typedef __attribute__((ext_vector_type(8))) short short8;
typedef __attribute__((ext_vector_type(4))) float f32x4;
using u32 = unsigned int;
using u16 = unsigned short;
using u64 = unsigned long long;

// ---------------------------------------------------------------------------
// Kernel P: pack adj (4096x4096 int32 0/1) into transposed bitmask.
// 4 independent nt-loads per iter (ILP=4) so the 64 MB read runs at HBM BW.
// ---------------------------------------------------------------------------
__global__ __launch_bounds__(256) void pack_mask_kernel(const int* __restrict__ adj,
                                                        u32* __restrict__ mask_t) {
    const int wid = (blockIdx.x * 256 + threadIdx.x) >> 6;
    const int lane = threadIdx.x & 63;
    for (int t = wid; t < 65536; t += 8192) {          // task = (row, 4-chunk group)
        const int r = t >> 4, c4 = t & 15;
        const int* base = adj + (size_t)r * 4096 + c4 * 256 + lane;
        int v0 = __builtin_nontemporal_load(base);
        int v1 = __builtin_nontemporal_load(base + 64);
        int v2 = __builtin_nontemporal_load(base + 128);
        int v3 = __builtin_nontemporal_load(base + 192);
        u64 b0 = __ballot(v0 > 0);
        u64 b1 = __ballot(v1 > 0);
        u64 b2 = __ballot(v2 > 0);
        u64 b3 = __ballot(v3 > 0);
        if (lane < 8) {                                 // lane k stores word-col c4*8+k
            u64 bv = (lane & 4) ? ((lane & 2) ? b3 : b2) : ((lane & 2) ? b1 : b0);
            u32 w = (u32)(bv >> ((lane & 1) << 5));
            mask_t[(size_t)(c4 * 8 + lane) * 4096 + r] = w;
        }
    }
}

// ---------------------------------------------------------------------------
// Kernel 1: h-partial = x @ W over one K-segment (K-split KS=4).
// ---------------------------------------------------------------------------
__global__ __launch_bounds__(256) void k1_xw(const float* __restrict__ x,
                                             const float* __restrict__ W,
                                             float* __restrict__ ph,
                                             int TILES) {
    __shared__ float xs[64][36];
    __shared__ float ws[32][64];
    const int b = blockIdx.y, rt = blockIdx.x, ks = blockIdx.z;
    const int tid = threadIdx.x;
    const int rg = tid >> 4, cg = tid & 15;
    const int r0 = rg * 4, c0 = cg * 4;
    const int kt0 = ks * TILES;
    const float* xb = x + ((size_t)b * 4096 + (size_t)rt * 64) * 512;

    float acc[4][4];
#pragma unroll
    for (int i = 0; i < 4; i++)
#pragma unroll
        for (int j = 0; j < 4; j++) acc[i][j] = 0.f;

    float4 px[2], pw[2];
#pragma unroll
    for (int it = 0; it < 2; it++) {
        int c = tid + it * 256;
        px[it] = *(const float4*)(xb + (size_t)(c >> 3) * 512 + kt0 * 32 + ((c & 7) << 2));
        pw[it] = *(const float4*)(W + (size_t)(kt0 * 32 + (c >> 4)) * 64 + ((c & 15) << 2));
    }
    for (int kt = kt0; kt < kt0 + TILES; kt++) {
        __syncthreads();
#pragma unroll
        for (int it = 0; it < 2; it++) {
            int c = tid + it * 256;
            *(float4*)&xs[c >> 3][(c & 7) << 2] = px[it];
            *(float4*)&ws[c >> 4][(c & 15) << 2] = pw[it];
        }
        __syncthreads();
        if (kt < kt0 + TILES - 1) {
            int k0 = (kt + 1) * 32;
#pragma unroll
            for (int it = 0; it < 2; it++) {
                int c = tid + it * 256;
                px[it] = *(const float4*)(xb + (size_t)(c >> 3) * 512 + k0 + ((c & 7) << 2));
                pw[it] = *(const float4*)(W + (size_t)(k0 + (c >> 4)) * 64 + ((c & 15) << 2));
            }
        }
#pragma unroll
        for (int k4 = 0; k4 < 32; k4 += 4) {
            float4 xv[4], wv[4];
#pragma unroll
            for (int rr = 0; rr < 4; rr++) xv[rr] = *(const float4*)&xs[r0 + rr][k4];
#pragma unroll
            for (int kk = 0; kk < 4; kk++) wv[kk] = *(const float4*)&ws[k4 + kk][c0];
#pragma unroll
            for (int rr = 0; rr < 4; rr++)
#pragma unroll
                for (int kk = 0; kk < 4; kk++) {
                    const float xvv = ((const float*)&xv[rr])[kk];
#pragma unroll
                    for (int cc = 0; cc < 4; cc++)
                        acc[rr][cc] = fmaf(xvv, ((const float*)&wv[kk])[cc], acc[rr][cc]);
                }
        }
    }
    float* pb = ph + (((size_t)(ks * 4 + b) * 4096) + rt * 64) * 64;
#pragma unroll
    for (int rr = 0; rr < 4; rr++)
        *(float4*)&pb[(size_t)(r0 + rr) * 64 + c0] = *(float4*)&acc[rr][0];
}

// ---------------------------------------------------------------------------
// Kernel 1c: sum K-split partials; epilogue: s1/s2 (pre-scaled), h^T bf16.
// ---------------------------------------------------------------------------
template <int KS>
__global__ __launch_bounds__(256) void k1c_fin(const float* __restrict__ ph,
                                               const float* __restrict__ a,
                                               u16* __restrict__ h_t,
                                               float* __restrict__ s1p,
                                               float* __restrict__ s2p) {
    const int b = blockIdx.y, rt = blockIdx.x;
    const int tid = threadIdx.x;
    const int rg = tid >> 4, cg = tid & 15;
    const int r0 = rg * 4, c0 = cg * 4;

    float4 v[KS][4];
#pragma unroll
    for (int s = 0; s < KS; s++) {
        const float* pb = ph + (((size_t)(s * 4 + b) * 4096) + rt * 64) * 64;
#pragma unroll
        for (int rr = 0; rr < 4; rr++)
            v[s][rr] = *(const float4*)&pb[(size_t)(r0 + rr) * 64 + c0];
    }
    float acc[4][4];
#pragma unroll
    for (int rr = 0; rr < 4; rr++) {
        acc[rr][0] = acc[rr][1] = acc[rr][2] = acc[rr][3] = 0.f;
#pragma unroll
        for (int s = 0; s < KS; s++) {
            acc[rr][0] += v[s][rr].x; acc[rr][1] += v[s][rr].y;
            acc[rr][2] += v[s][rr].z; acc[rr][3] += v[s][rr].w;
        }
    }
    float s1v[4], s2v[4];
#pragma unroll
    for (int rr = 0; rr < 4; rr++) { s1v[rr] = 0.f; s2v[rr] = 0.f; }
#pragma unroll
    for (int cc = 0; cc < 4; cc++) {
        float a1 = a[c0 + cc], a2 = a[64 + c0 + cc];
#pragma unroll
        for (int rr = 0; rr < 4; rr++) {
            s1v[rr] = fmaf(acc[rr][cc], a1, s1v[rr]);
            s2v[rr] = fmaf(acc[rr][cc], a2, s2v[rr]);
        }
    }
#pragma unroll
    for (int d = 1; d < 16; d <<= 1) {
#pragma unroll
        for (int rr = 0; rr < 4; rr++) {
            s1v[rr] += __shfl_xor(s1v[rr], d);
            s2v[rr] += __shfl_xor(s2v[rr], d);
        }
    }
    if (cg == 0) {
#pragma unroll
        for (int rr = 0; rr < 4; rr++) {
            int row = rt * 64 + r0 + rr;
            s1p[b * 4096 + row] = s1v[rr] * LOG2E;
            s2p[b * 4096 + row] = s2v[rr] * LOG2E;
        }
    }
#pragma unroll
    for (int cc = 0; cc < 4; cc++) {
        u32 b0 = __float_as_uint(acc[0][cc]) + 0x8000u;
        u32 b1 = __float_as_uint(acc[1][cc]) + 0x8000u;
        u32 b2 = __float_as_uint(acc[2][cc]) + 0x8000u;
        u32 b3 = __float_as_uint(acc[3][cc]) + 0x8000u;
        uint2 u;
        u.x = (b0 >> 16) | (b1 & 0xffff0000u);
        u.y = (b2 >> 16) | (b3 & 0xffff0000u);
        *(uint2*)(h_t + ((size_t)(b * 64 + c0 + cc)) * 4096 + rt * 64 + r0) = u;
    }
}

// ---------------------------------------------------------------------------
// Kernel 2: fused masked-softmax-numerator GEMM.
// Liveness-bounded pipeline:
//  - mask: rolling 4-deep window, distance-4 prefetch. CONSUME BEFORE
//    PREFETCH: (s+4)&3 == s&3, so the step-s mask must be read out of the
//    window before the step-s+4 load overwrites the slot (r5 bug: the
//    prefetch preceded the read -> every step used the mask 4 steps ahead).
//  - B-frags: 2-deep ping-pong from L2-resident h_t, issued 1 iter ahead.
//  - s2: LDS tile (one fill + one barrier), ds_read on lgkm counter.
// Peak ~64 VGPR + 16 acc -> no spills.
// ---------------------------------------------------------------------------
template <int NSTEP>
__global__ __launch_bounds__(256, 4) void k2_attn(const u16* __restrict__ h_t,
                                                  const u32* __restrict__ mask_t,
                                                  const float* __restrict__ s1p,
                                                  const float* __restrict__ s2p,
                                                  float* __restrict__ part,
                                                  float* __restrict__ lp) {
    constexpr int JSEG = NSTEP * 32;
    __shared__ float s2l[JSEG];
    const int b = blockIdx.y, seg = blockIdx.z, rb = blockIdx.x;
    const int tid = threadIdx.x, wave = tid >> 6, lane = tid & 63;
    const int m = lane & 15, quad = lane >> 4;
    const int row = rb * 64 + wave * 16 + m;
    const int jstart = seg * JSEG;
    const float t1 = s1p[b * 4096 + row];
    const u16* hb0 = h_t + ((size_t)b * 64 + m) * 4096 + jstart + quad * 8;
    const u32* mrow = mask_t + (size_t)(jstart >> 5) * 4096 + row;

    for (int t = tid; t < (JSEG >> 2); t += 256)
        ((float4*)s2l)[t] = ((const float4*)(s2p + b * 4096 + jstart))[t];

    f32x4 acc[4];
#pragma unroll
    for (int ot = 0; ot < 4; ot++) acc[ot] = (f32x4){0.f, 0.f, 0.f, 0.f};
    float lsA = 0.f, lsB = 0.f;

    union BU { uint4 q; short8 v; };
    BU bf[2][4];
    u32 mw[4];
#pragma unroll
    for (int s = 0; s < 4; s++) mw[s] = mrow[(size_t)s * 4096];   // mask window 0..3
#pragma unroll
    for (int ot = 0; ot < 4; ot++)                                 // B step 0
        bf[0][ot].q = *(const uint4*)(hb0 + (size_t)ot * 16 * 4096);
    __syncthreads();   // s2l ready (only barrier in the kernel)

#pragma unroll 4
    for (int s = 0; s < NSTEP; s++) {
        const int cur = s & 1, nxt = cur ^ 1;
        // READ the current mask word FIRST (slot (s+4)&3 aliases s&3)
        const u32 mws = mw[s & 3] >> (quad * 8);
        if (s + 1 < NSTEP) {       // B prefetch, 1 iter ahead
#pragma unroll
            for (int ot = 0; ot < 4; ot++)
                bf[nxt][ot].q = *(const uint4*)(hb0 + (s + 1) * 32 + (size_t)ot * 16 * 4096);
        }
        if (s + 4 < NSTEP)         // mask prefetch, 4 iters ahead (stays oldest)
            mw[(s + 4) & 3] = mrow[(size_t)(s + 4) * 4096];

        const float4 sa = *(const float4*)&s2l[s * 32 + quad * 8];
        const float4 sb = *(const float4*)&s2l[s * 32 + quad * 8 + 4];
        const float sv[8] = {sa.x, sa.y, sa.z, sa.w, sb.x, sb.y, sb.z, sb.w};
        union { u32 u[4]; short8 v; } af;
#pragma unroll
        for (int p = 0; p < 4; p++) {
            float t0 = t1 + sv[2 * p];
            float u0 = fmaxf(t0, 0.2f * t0);                     // leaky-relu (log2 domain)
            float w0 = __builtin_amdgcn_exp2f(u0);
            u32 m0 = (u32)(((int)(mws << (31 - 2 * p))) >> 31);  // bit -> all-ones/0
            u32 w0u = __float_as_uint(w0) & m0;                  // masked -> +0.0
            float t2 = t1 + sv[2 * p + 1];
            float u2 = fmaxf(t2, 0.2f * t2);
            float w1 = __builtin_amdgcn_exp2f(u2);
            u32 m1 = (u32)(((int)(mws << (30 - 2 * p))) >> 31);
            u32 w1u = __float_as_uint(w1) & m1;
            lsA += __uint_as_float(w0u);                         // denom (pre-round)
            lsB += __uint_as_float(w1u);
            // round-half-up bf16 pack: hi16 of (w+0x8000)
            af.u[p] = __builtin_amdgcn_perm(w1u + 0x8000u, w0u + 0x8000u, 0x07060302u);
        }
#pragma unroll
        for (int ot = 0; ot < 4; ot++)
            acc[ot] = __builtin_amdgcn_mfma_f32_16x16x32_bf16(af.v, bf[cur][ot].v,
                                                              acc[ot], 0, 0, 0);
    }
    // C/D layout: col=lane&15 (=o sub-index), row=quad*4+reg (=attention row)
    float* pb = part + (((size_t)(seg * 4 + b) * 4096) + rb * 64 + wave * 16) * 64;
#pragma unroll
    for (int ot = 0; ot < 4; ot++)
#pragma unroll
        for (int r = 0; r < 4; r++)
            pb[(quad * 4 + r) * 64 + ot * 16 + m] = acc[ot][r];
    lp[((size_t)(seg * 4 + b) * 4096 + row) * 4 + quad] = lsA + lsB;
}

// ---------------------------------------------------------------------------
// Kernel 3: combine j-split partials, normalize, elu.
// ---------------------------------------------------------------------------
template <int S>
__global__ __launch_bounds__(256) void k3_fin(const float* __restrict__ part,
                                              const float* __restrict__ lp,
                                              float* __restrict__ out) {
    int idx = blockIdx.x * 256 + threadIdx.x;    // 262144 = 4*4096*16
    int o4 = (idx & 15) << 2;
    int bi = idx >> 4;
    float4 pv[S], lv[S];
#pragma unroll
    for (int s = 0; s < S; s++) {
        pv[s] = *(const float4*)&part[((size_t)s * 16384 + bi) * 64 + o4];
        lv[s] = *(const float4*)&lp[((size_t)s * 16384 + bi) * 4];
    }
    float p0 = 0.f, p1 = 0.f, p2 = 0.f, p3 = 0.f, l = 0.f;
#pragma unroll
    for (int s = 0; s < S; s++) {
        p0 += pv[s].x; p1 += pv[s].y; p2 += pv[s].z; p3 += pv[s].w;
        l += (lv[s].x + lv[s].y) + (lv[s].z + lv[s].w);
    }
    float rl = 1.f / l;
    p0 *= rl; p1 *= rl; p2 *= rl; p3 *= rl;
    float4 o;
    o.x = p0 > 0.f ? p0 : __builtin_amdgcn_exp2f(p0 * LOG2E) - 1.f;
    o.y = p1 > 0.f ? p1 : __builtin_amdgcn_exp2f(p1 * LOG2E) - 1.f;
    o.z = p2 > 0.f ? p2 : __builtin_amdgcn_exp2f(p2 * LOG2E) - 1.f;
    o.w = p3 > 0.f ? p3 : __builtin_amdgcn_exp2f(p3 * LOG2E) - 1.f;
    *(float4*)&out[(size_t)bi * 64 + o4] = o;
}

// ---------------------------------------------------------------------------
extern "C" void kernel_launch(void* const* d_in, const int* in_sizes, int n_in,
                              void* d_out, int out_size, void* d_ws, size_t ws_size,
                              hipStream_t stream) {
    const float* x  = (const float*)d_in[0];
    const int* adj  = (const int*)d_in[1];
    const float* W  = (const float*)d_in[2];
    const float* a  = (const float*)d_in[3];
    float* out = (float*)d_out;
    char* ws = (char*)d_ws;

    // workspace layout
    u16* h_t   = (u16*)ws;                         // 2 MB
    u32* maskt = (u32*)(ws + (2 << 20));           // 2 MB
    float* s1p = (float*)(ws + (4 << 20));         // 64 KB
    float* s2p = s1p + 16384;                      // 64 KB
    float* lp  = s2p + 16384;                      // S*256 KB
    size_t base = (4u << 20) + 2 * 65536;
    int S = 4;                                     // k2 j-split: 1024 WGs = 4 WGs/CU
    while (S > 1 && base + (size_t)S * (262144 + 4194304) > ws_size) S >>= 1;
    float* part = (float*)(ws + base + (size_t)S * 262144);   // S*4 MB
    // k1 K-split partials alias the part buffer (free until k2 writes it)
    int KS = 4;
    while (KS > 1 && base + (size_t)S * 262144 + (size_t)KS * 4194304 > ws_size) KS >>= 1;

    pack_mask_kernel<<<2048, 256, 0, stream>>>(adj, maskt);
    k1_xw<<<dim3(64, 4, KS), 256, 0, stream>>>(x, W, part, 16 / KS);
    if (KS == 4)      k1c_fin<4><<<dim3(64, 4), 256, 0, stream>>>(part, a, h_t, s1p, s2p);
    else if (KS == 2) k1c_fin<2><<<dim3(64, 4), 256, 0, stream>>>(part, a, h_t, s1p, s2p);
    else              k1c_fin<1><<<dim3(64, 4), 256, 0, stream>>>(part, a, h_t, s1p, s2p);
    if (S == 4)      k2_attn<32><<<dim3(64, 4, 4), 256, 0, stream>>>(h_t, maskt, s1p, s2p, part, lp);
    else if (S == 2) k2_attn<64><<<dim3(64, 4, 2), 256, 0, stream>>>(h_t, maskt, s1p, s2p, part, lp);
    else             k2_attn<128><<<dim3(64, 4, 1), 256, 0, stream>>>(h_t, maskt, s1p, s2p, part, lp);
    if (S == 4)      k3_fin<4><<<1024, 256, 0, stream>>>(part, lp, out);
    else if (S == 2) k3_fin<2><<<1024, 256, 0, stream>>>(part, lp, out);
    else             k3_fin<1><<<1024, 256, 0, stream>>>(part, lp, out);
}